// Round 4
// baseline (250.904 us; speedup 1.0000x reference)
//
#include <hip/hip_runtime.h>
#include <hip/hip_bf16.h>

typedef __hip_bfloat16 bf16;
typedef __attribute__((ext_vector_type(8))) short bf16x8;
typedef __attribute__((ext_vector_type(4))) float f32x4;

// Geometry (hardcoded): B=2, T=16, H=32, W=32, C=512, heads=8, hd=64,
// win=(8,8,8) -> no padding. 64 windows x 512 tokens; M = 32768 rows.
#define MROWS 32768
#define CDIM 512

__device__ __forceinline__ int win_to_src_row(int m) {
  int win = m >> 9, l = m & 511;
  int b = win >> 5, rr = win & 31;
  int nt = rr >> 4, nh = (rr >> 2) & 3, nw = rr & 3;
  int wt = l >> 6, wh = (l >> 3) & 7, ww = l & 7;
  int tt = nt * 8 + wt, hh = nh * 8 + wh, wp = nw * 8 + ww;
  return (b << 14) + (tt << 10) + (hh << 5) + wp;
}

__device__ __forceinline__ unsigned short bf16bits(bf16 h) {
  return __builtin_bit_cast(unsigned short, h);
}

__device__ __forceinline__ ushort4 pack4(f32x4 a) {
  ushort4 o;
  o.x = bf16bits(__float2bfloat16(a[0]));
  o.y = bf16bits(__float2bfloat16(a[1]));
  o.z = bf16bits(__float2bfloat16(a[2]));
  o.w = bf16bits(__float2bfloat16(a[3]));
  return o;
}

// XCD-chunked bijective block swizzle (requires n % 8 == 0)
__device__ __forceinline__ int xcd_chunk(int bx, int n) {
  return (bx & 7) * (n >> 3) + (bx >> 3);
}

// ---------------- pass 0a: weight transpose + fp32->bf16 ----------------
__global__ __launch_bounds__(256) void transpose_cvt_kernel(
    const float* __restrict__ src, bf16* __restrict__ dst, int R, int C) {
  __shared__ float tile[32][33];
  int bc = blockIdx.x * 32, br = blockIdx.y * 32;
  int tx = threadIdx.x, ty = threadIdx.y;  // (32,8)
#pragma unroll
  for (int i = 0; i < 32; i += 8)
    tile[ty + i][tx] = src[(size_t)(br + ty + i) * C + bc + tx];
  __syncthreads();
#pragma unroll
  for (int i = 0; i < 32; i += 8)
    dst[(size_t)(bc + ty + i) * R + br + tx] = __float2bfloat16(tile[tx][ty + i]);
}

// ---------------- pass 0b: x permute to window order + fp32->bf16 ----------------
__global__ __launch_bounds__(256) void perm_x_kernel(const float* __restrict__ x,
                                                     bf16* __restrict__ xw) {
  const int total = MROWS * (CDIM / 4);  // float4 units
  for (int i = blockIdx.x * 256 + threadIdx.x; i < total; i += 2048 * 256) {
    int m = i >> 7, c4 = (i & 127) * 4;
    int src = win_to_src_row(m);
    float4 v = *(const float4*)(x + (size_t)src * CDIM + c4);
    ushort4 o;
    o.x = bf16bits(__float2bfloat16(v.x));
    o.y = bf16bits(__float2bfloat16(v.y));
    o.z = bf16bits(__float2bfloat16(v.z));
    o.w = bf16bits(__float2bfloat16(v.w));
    *(ushort4*)(xw + (size_t)m * CDIM + c4) = o;
  }
}

__device__ __forceinline__ void gload16(const bf16* g, const bf16* l) {
  __builtin_amdgcn_global_load_lds(
      (const __attribute__((address_space(1))) unsigned int*)g,
      (__attribute__((address_space(3))) unsigned int*)l, 16, 0, 0);
}

// ---------------- fused QKV-projection + windowed attention ----------------
// grid = 512 blocks (wh = win*8 + head), 512 threads = 8 waves; wave w owns
// tokens [w*64, w*64+64).
// LDS map (160 KiB total):
//   [0,      32768): X-tile [512 rows][32 k] (swizzled), later P tiles (8 waves x 4KB)
//   [32768,  98304): K_lds [512 tok][64 d] bf16, rows 128B, XOR-swizzled
//   [98304, 163840): first Q-bounce [512][64] (rows 128B swz), then V^T [64 d][512 tok]
// Pass A (swapped mfma: regs hold d-contiguous): q,k -> packed 8B LDS writes.
// Pass B (normal mfma: regs hold tok-contiguous): v -> packed V^T writes.
// Attention: round-3 proven inner loop, all operands from LDS.
__global__ __launch_bounds__(512, 2) void fused_qkv_attn_kernel(
    const bf16* __restrict__ xw, const bf16* __restrict__ wqkvT,
    bf16* __restrict__ o_ws) {
  __shared__ __align__(16) char smem[163840];
  bf16* Xl = (bf16*)smem;
  char* Kl = smem + 32768;
  char* Vl = smem + 98304;  // Q bounce, then V^T
  char* Ql = Vl;

  int wh = xcd_chunk(blockIdx.x, 512);
  int win = wh >> 3, head = wh & 7;
  int t = threadIdx.x, lane = t & 63, w = t >> 6;
  int l15 = lane & 15, lh = lane >> 4;
  const bf16* xb = xw + (size_t)win * (512 * 512);

  // ---- pass A: q (cols 0-63) and k (cols 64-127), swapped orientation ----
  f32x4 aqk[8][4] = {};  // [col-tile][tok-tile]
  for (int kt = 0; kt < 16; ++kt) {
    bf16x8 aW[8];
#pragma unroll
    for (int mi = 0; mi < 8; ++mi) {
      int wrow = (mi < 4 ? head * 64 + mi * 16 : 512 + head * 64 + (mi - 4) * 16) + l15;
      aW[mi] = *(const bf16x8*)(wqkvT + (size_t)wrow * 512 + kt * 32 + lh * 8);
    }
    __syncthreads();
#pragma unroll
    for (int i = 0; i < 4; ++i) {
      int f = i * 512 + t;
      int row = f >> 2, cb = f & 3;
      gload16(xb + (size_t)row * 512 + kt * 32 + (cb ^ (row & 3)) * 8,
              (const bf16*)((char*)Xl + (i * 512 + w * 64) * 16));
    }
    __syncthreads();
    bf16x8 bX[4];
#pragma unroll
    for (int ti = 0; ti < 4; ++ti) {
      int row = w * 64 + ti * 16 + l15;
      bX[ti] = *(const bf16x8*)((const char*)Xl + row * 64 + ((lh * 16) ^ ((row & 3) << 4)));
    }
#pragma unroll
    for (int mi = 0; mi < 8; ++mi)
#pragma unroll
      for (int ti = 0; ti < 4; ++ti)
        aqk[mi][ti] = __builtin_amdgcn_mfma_f32_16x16x32_bf16(aW[mi], bX[ti], aqk[mi][ti], 0, 0, 0);
  }
  // epilogue A: K -> Kl, Q -> Ql (lane l15 = tok, regs = 4 contiguous d)
#pragma unroll
  for (int mi = 0; mi < 8; ++mi)
#pragma unroll
    for (int ti = 0; ti < 4; ++ti) {
      int tok = w * 64 + ti * 16 + l15;
      int d0 = (mi & 3) * 16 + lh * 4;
      char* base = (mi < 4) ? Ql : Kl;
      *(ushort4*)(base + tok * 128 + ((d0 * 2) ^ ((tok & 7) << 4))) = pack4(aqk[mi][ti]);
    }
  __syncthreads();
  bf16x8 qf[4][2];
#pragma unroll
  for (int qi = 0; qi < 4; ++qi) {
    int tok = w * 64 + qi * 16 + l15;
#pragma unroll
    for (int kk = 0; kk < 2; ++kk)
      qf[qi][kk] = *(const bf16x8*)(Ql + tok * 128 + ((kk * 64 + lh * 16) ^ ((tok & 7) << 4)));
  }
  __syncthreads();

  // ---- pass B: v (cols 128-191), normal orientation ----
  f32x4 av[4][4] = {};  // [tok-tile][d-tile]
  for (int kt = 0; kt < 16; ++kt) {
    bf16x8 bW[4];
#pragma unroll
    for (int nj = 0; nj < 4; ++nj) {
      int wrow = 1024 + head * 64 + nj * 16 + l15;
      bW[nj] = *(const bf16x8*)(wqkvT + (size_t)wrow * 512 + kt * 32 + lh * 8);
    }
    __syncthreads();
#pragma unroll
    for (int i = 0; i < 4; ++i) {
      int f = i * 512 + t;
      int row = f >> 2, cb = f & 3;
      gload16(xb + (size_t)row * 512 + kt * 32 + (cb ^ (row & 3)) * 8,
              (const bf16*)((char*)Xl + (i * 512 + w * 64) * 16));
    }
    __syncthreads();
    bf16x8 aX[4];
#pragma unroll
    for (int ti = 0; ti < 4; ++ti) {
      int row = w * 64 + ti * 16 + l15;
      aX[ti] = *(const bf16x8*)((const char*)Xl + row * 64 + ((lh * 16) ^ ((row & 3) << 4)));
    }
#pragma unroll
    for (int ti = 0; ti < 4; ++ti)
#pragma unroll
      for (int nj = 0; nj < 4; ++nj)
        av[ti][nj] = __builtin_amdgcn_mfma_f32_16x16x32_bf16(aX[ti], bW[nj], av[ti][nj], 0, 0, 0);
  }
  // epilogue B: V^T -> Vl (lane l15 = d, regs = 4 contiguous tok)
#pragma unroll
  for (int ti = 0; ti < 4; ++ti)
#pragma unroll
    for (int nj = 0; nj < 4; ++nj) {
      int d = nj * 16 + l15;
      int tok0 = w * 64 + ti * 16 + lh * 4;
      *(ushort4*)(Vl + d * 1024 + ((tok0 * 2) ^ ((d & 7) << 4))) = pack4(av[ti][nj]);
    }
  __syncthreads();

  // ---- attention: wave w handles q-rows [w*64, w*64+64) ----
  const float c_scale = 0.18033688011112042f;  // 0.125 * log2(e)
  int q0 = w * 64;
  f32x4 acco[4][4] = {};
  float lsum[4][4] = {};
  for (int kt = 0; kt < 8; ++kt) {
    bf16x8 kf[4][2], vf[4][2];
#pragma unroll
    for (int kj = 0; kj < 4; ++kj) {
      int tok = kt * 64 + kj * 16 + l15;
#pragma unroll
      for (int kk = 0; kk < 2; ++kk)
        kf[kj][kk] = *(const bf16x8*)(Kl + tok * 128 + ((kk * 64 + lh * 16) ^ ((tok & 7) << 4)));
    }
#pragma unroll
    for (int nj = 0; nj < 4; ++nj) {
      int d = nj * 16 + l15;
#pragma unroll
      for (int kk = 0; kk < 2; ++kk)
        vf[nj][kk] = *(const bf16x8*)(Vl + d * 1024 + ((kt * 128 + kk * 64 + lh * 16) ^ ((d & 7) << 4)));
    }
#pragma unroll
    for (int qi = 0; qi < 4; ++qi) {
      f32x4 s[4] = {};
#pragma unroll
      for (int kj = 0; kj < 4; ++kj)
#pragma unroll
        for (int kk = 0; kk < 2; ++kk)
          s[kj] = __builtin_amdgcn_mfma_f32_16x16x32_bf16(qf[qi][kk], kf[kj][kk], s[kj], 0, 0, 0);
#pragma unroll
      for (int kj = 0; kj < 4; ++kj)
#pragma unroll
        for (int r = 0; r < 4; ++r) {
          float p = __builtin_exp2f(s[kj][r] * c_scale);
          s[kj][r] = p;
          lsum[qi][r] += p;
        }
      char* myP = smem + w * 4096 + (qi & 1) * 2048;
#pragma unroll
      for (int kj = 0; kj < 4; ++kj)
#pragma unroll
        for (int r = 0; r < 4; ++r) {
          int prow = lh * 4 + r, pcol = kj * 16 + l15;
          *(bf16*)(myP + prow * 128 + ((pcol * 2) ^ ((prow & 7) << 4))) =
              __float2bfloat16(s[kj][r]);
        }
      bf16x8 pa[2];
#pragma unroll
      for (int kk = 0; kk < 2; ++kk)
        pa[kk] = *(const bf16x8*)(myP + l15 * 128 + ((kk * 64 + lh * 16) ^ ((l15 & 7) << 4)));
#pragma unroll
      for (int nj = 0; nj < 4; ++nj)
#pragma unroll
        for (int kk = 0; kk < 2; ++kk)
          acco[qi][nj] = __builtin_amdgcn_mfma_f32_16x16x32_bf16(pa[kk], vf[nj][kk],
                                                                 acco[qi][nj], 0, 0, 0);
    }
  }
#pragma unroll
  for (int qi = 0; qi < 4; ++qi) {
    float inv[4];
#pragma unroll
    for (int r = 0; r < 4; ++r) {
      float v = lsum[qi][r];
      v += __shfl_xor(v, 1);
      v += __shfl_xor(v, 2);
      v += __shfl_xor(v, 4);
      v += __shfl_xor(v, 8);
      inv[r] = __frcp_rn(v);
    }
#pragma unroll
    for (int nj = 0; nj < 4; ++nj)
#pragma unroll
      for (int r = 0; r < 4; ++r) {
        int row = q0 + qi * 16 + lh * 4 + r;
        int d = nj * 16 + l15;
        o_ws[((size_t)win * 512 + row) * 512 + head * 64 + d] =
            __float2bfloat16(acco[qi][nj][r] * inv[r]);
      }
  }
}

// ---------------- proj GEMM: out = o_ws @ w_projT^T + bias, un-partitioned ----
#define BM 128
#define BN 128
#define BK 64

__global__ __launch_bounds__(256) void proj_gemm_kernel(
    const bf16* __restrict__ A, const bf16* __restrict__ Bt, int Ntiles,
    float* __restrict__ out, const float* __restrict__ bias) {
  __shared__ __align__(16) bf16 Asl[BM * BK];
  __shared__ __align__(16) bf16 Bsl[BN * BK];
  const int K = 512;
  int l2 = xcd_chunk(blockIdx.x, gridDim.x);
  int bn = (l2 >> 3) % Ntiles;
  int bm = (l2 & 7) + (l2 / (8 * Ntiles)) * 8;
  int t = threadIdx.x, lane = t & 63, w = t >> 6;
  int wr = w >> 1, wc = w & 1;
  int l15 = lane & 15, lh = lane >> 4;
  f32x4 acc[4][4] = {};

  for (int kt = 0; kt < K; kt += BK) {
    __syncthreads();
#pragma unroll
    for (int i = 0; i < 4; ++i) {
      int f = i * 256 + t;
      int row = f >> 3, cb = f & 7;
      gload16(A + (size_t)(bm * BM + row) * K + kt + cb * 8, &Asl[(i * 256 + w * 64) * 8]);
    }
#pragma unroll
    for (int i = 0; i < 4; ++i) {
      int f = i * 256 + t;
      int row = f >> 3, cb = f & 7;
      gload16(Bt + (size_t)(bn * BN + row) * K + kt + cb * 8, &Bsl[(i * 256 + w * 64) * 8]);
    }
    __syncthreads();
#pragma unroll
    for (int kk = 0; kk < 2; ++kk) {
      bf16x8 af[4], bfr[4];
#pragma unroll
      for (int mi = 0; mi < 4; ++mi)
        af[mi] = *(const bf16x8*)&Asl[(wr * 64 + mi * 16 + l15) * BK + kk * 32 + lh * 8];
#pragma unroll
      for (int nj = 0; nj < 4; ++nj)
        bfr[nj] = *(const bf16x8*)&Bsl[(wc * 64 + nj * 16 + l15) * BK + kk * 32 + lh * 8];
#pragma unroll
      for (int mi = 0; mi < 4; ++mi)
#pragma unroll
        for (int nj = 0; nj < 4; ++nj)
          acc[mi][nj] = __builtin_amdgcn_mfma_f32_16x16x32_bf16(af[mi], bfr[nj], acc[mi][nj], 0, 0, 0);
    }
  }
#pragma unroll
  for (int mi = 0; mi < 4; ++mi) {
    int row = bm * BM + wr * 64 + mi * 16 + lh * 4;
#pragma unroll
    for (int r = 0; r < 4; ++r) {
      int srow = win_to_src_row(row + r);
      float* op = out + (size_t)srow * CDIM;
#pragma unroll
      for (int nj = 0; nj < 4; ++nj) {
        int col = bn * BN + wc * 64 + nj * 16 + l15;
        op[col] = acc[mi][nj][r] + bias[col];
      }
    }
  }
}

extern "C" void kernel_launch(void* const* d_in, const int* in_sizes, int n_in,
                              void* d_out, int out_size, void* d_ws, size_t ws_size,
                              hipStream_t stream) {
  const float* x = (const float*)d_in[0];
  const float* w_qkv = (const float*)d_in[1];
  const float* w_proj = (const float*)d_in[2];
  const float* b_proj = (const float*)d_in[3];
  float* out = (float*)d_out;

  // workspace: xw 32MB | o_ws 32MB | wqkvT 1.5MB | wprojT 0.5MB
  const size_t OFF_O = 33554432;
  const size_t OFF_WQ = OFF_O + 33554432;
  const size_t OFF_WP = OFF_WQ + 1572864;
  const size_t NEED = OFF_WP + 524288;
  if (ws_size < NEED) return;

  char* ws = (char*)d_ws;
  bf16* xw = (bf16*)ws;
  bf16* o_ws = (bf16*)(ws + OFF_O);
  bf16* wqkvT = (bf16*)(ws + OFF_WQ);
  bf16* wprojT = (bf16*)(ws + OFF_WP);

  transpose_cvt_kernel<<<dim3(1536 / 32, 512 / 32), dim3(32, 8), 0, stream>>>(w_qkv, wqkvT, 512, 1536);
  transpose_cvt_kernel<<<dim3(512 / 32, 512 / 32), dim3(32, 8), 0, stream>>>(w_proj, wprojT, 512, 512);
  perm_x_kernel<<<2048, 256, 0, stream>>>(x, xw);
  fused_qkv_attn_kernel<<<512, 512, 0, stream>>>(xw, wqkvT, o_ws);
  proj_gemm_kernel<<<1024, 256, 0, stream>>>(o_ws, wprojT, 4, out, b_proj);
}

// Round 5
// 240.111 us; speedup vs baseline: 1.0449x; 1.0449x over previous
//
#include <hip/hip_runtime.h>
#include <hip/hip_bf16.h>

typedef __hip_bfloat16 bf16;
typedef __attribute__((ext_vector_type(8))) short bf16x8;
typedef __attribute__((ext_vector_type(4))) float f32x4;

// Geometry (hardcoded): B=2, T=16, H=32, W=32, C=512, heads=8, hd=64,
// win=(8,8,8) -> no padding. 64 windows x 512 tokens; M = 32768 rows.
#define MROWS 32768
#define CDIM 512
#define SEL_STRIDE (512*512*64)  // elems per q/k/v section
// q,k sections: [wh=512][tok=512][d=64] row-major
// v section:    [wh=512][d=64][tok=512]  (transposed)

__device__ __forceinline__ int win_to_src_row(int m) {
  int win = m >> 9, l = m & 511;
  int b = win >> 5, rr = win & 31;
  int nt = rr >> 4, nh = (rr >> 2) & 3, nw = rr & 3;
  int wt = l >> 6, wh = (l >> 3) & 7, ww = l & 7;
  int tt = nt * 8 + wt, hh = nh * 8 + wh, wp = nw * 8 + ww;
  return (b << 14) + (tt << 10) + (hh << 5) + wp;
}

__device__ __forceinline__ unsigned short bf16bits(bf16 h) {
  return __builtin_bit_cast(unsigned short, h);
}

__device__ __forceinline__ ushort4 pack4(f32x4 a) {
  ushort4 o;
  o.x = bf16bits(__float2bfloat16(a[0]));
  o.y = bf16bits(__float2bfloat16(a[1]));
  o.z = bf16bits(__float2bfloat16(a[2]));
  o.w = bf16bits(__float2bfloat16(a[3]));
  return o;
}

// XCD-chunked bijective block swizzle (requires n % 8 == 0)
__device__ __forceinline__ int xcd_chunk(int bx, int n) {
  return (bx & 7) * (n >> 3) + (bx >> 3);
}

// ---------------- pass 0a: weight transpose + fp32->bf16 ----------------
__global__ __launch_bounds__(256) void transpose_cvt_kernel(
    const float* __restrict__ src, bf16* __restrict__ dst, int R, int C) {
  __shared__ float tile[32][33];
  int bc = blockIdx.x * 32, br = blockIdx.y * 32;
  int tx = threadIdx.x, ty = threadIdx.y;  // (32,8)
#pragma unroll
  for (int i = 0; i < 32; i += 8)
    tile[ty + i][tx] = src[(size_t)(br + ty + i) * C + bc + tx];
  __syncthreads();
#pragma unroll
  for (int i = 0; i < 32; i += 8)
    dst[(size_t)(bc + ty + i) * R + br + tx] = __float2bfloat16(tile[tx][ty + i]);
}

// ---------------- pass 0b: x permute to window order + fp32->bf16 ----------------
__global__ __launch_bounds__(256) void perm_x_kernel(const float* __restrict__ x,
                                                     bf16* __restrict__ xw) {
  const int total = MROWS * (CDIM / 4);  // float4 units
  for (int i = blockIdx.x * 256 + threadIdx.x; i < total; i += 2048 * 256) {
    int m = i >> 7, c4 = (i & 127) * 4;
    int src = win_to_src_row(m);
    float4 v = *(const float4*)(x + (size_t)src * CDIM + c4);
    ushort4 o;
    o.x = bf16bits(__float2bfloat16(v.x));
    o.y = bf16bits(__float2bfloat16(v.y));
    o.z = bf16bits(__float2bfloat16(v.z));
    o.w = bf16bits(__float2bfloat16(v.w));
    *(ushort4*)(xw + (size_t)m * CDIM + c4) = o;
  }
}

// ---------------- shared GEMM: C[M,N] = A[M,512] @ Bt[N,512]^T ----------------
#define BM 128
#define BN 128
#define BK 64

__device__ __forceinline__ void gload16(const bf16* g, const bf16* l) {
  __builtin_amdgcn_global_load_lds(
      (const __attribute__((address_space(1))) unsigned int*)g,
      (__attribute__((address_space(3))) unsigned int*)l, 16, 0, 0);
}

// MODE 0, SWAP 1: q/k tiles (bn0=0, cols 0-1023). Swapped MFMA: regs hold 4
//   contiguous d -> packed ushort4 row-major scatter.
// MODE 0, SWAP 0: v tiles (bn0=8, cols 1024-1535). Normal MFMA: regs hold 4
//   contiguous toks -> packed ushort4 transposed scatter.
// MODE 1: proj (fp32 d_out with window un-partition + bias).
template <int MODE, int SWAP>
__global__ __launch_bounds__(256) void gemm_bt_kernel(
    const bf16* __restrict__ A, const bf16* __restrict__ Bt, int Ntiles, int bn0,
    bf16* __restrict__ qkv_out, float* __restrict__ out,
    const float* __restrict__ bias) {
  __shared__ __align__(16) bf16 Asl[BM * BK];
  __shared__ __align__(16) bf16 Bsl[BN * BK];
  const int K = 512;
  int l2 = xcd_chunk(blockIdx.x, gridDim.x);
  int bn = bn0 + (l2 >> 3) % Ntiles;
  int bm = (l2 & 7) + (l2 / (8 * Ntiles)) * 8;
  int t = threadIdx.x, lane = t & 63, w = t >> 6;
  int wr = w >> 1, wc = w & 1;  // 2x2 waves, 64x64 each
  int l15 = lane & 15, lh = lane >> 4;
  f32x4 acc[4][4] = {};

  for (int kt = 0; kt < K; kt += BK) {
    __syncthreads();
#pragma unroll
    for (int i = 0; i < 4; ++i) {
      int f = i * 256 + t;
      int row = f >> 3, cb = f & 7;
      gload16(A + (size_t)(bm * BM + row) * K + kt + cb * 8,
              &Asl[(i * 256 + w * 64) * 8]);
    }
#pragma unroll
    for (int i = 0; i < 4; ++i) {
      int f = i * 256 + t;
      int row = f >> 3, cb = f & 7;
      gload16(Bt + (size_t)(bn * BN + row) * K + kt + cb * 8,
              &Bsl[(i * 256 + w * 64) * 8]);
    }
    __syncthreads();
#pragma unroll
    for (int kk = 0; kk < 2; ++kk) {
      bf16x8 af[4], bfr[4];
#pragma unroll
      for (int mi = 0; mi < 4; ++mi)
        af[mi] = *(const bf16x8*)&Asl[(wr * 64 + mi * 16 + l15) * BK + kk * 32 + lh * 8];
#pragma unroll
      for (int nj = 0; nj < 4; ++nj)
        bfr[nj] = *(const bf16x8*)&Bsl[(wc * 64 + nj * 16 + l15) * BK + kk * 32 + lh * 8];
#pragma unroll
      for (int mi = 0; mi < 4; ++mi)
#pragma unroll
        for (int nj = 0; nj < 4; ++nj) {
          if (SWAP)  // D[c][tok]: row(lh*4+r)=W-col c, col(l15)=tok
            acc[mi][nj] = __builtin_amdgcn_mfma_f32_16x16x32_bf16(
                bfr[nj], af[mi], acc[mi][nj], 0, 0, 0);
          else       // D[tok][c]: row(lh*4+r)=tok, col(l15)=c
            acc[mi][nj] = __builtin_amdgcn_mfma_f32_16x16x32_bf16(
                af[mi], bfr[nj], acc[mi][nj], 0, 0, 0);
        }
    }
  }

  if (MODE == 0 && SWAP == 1) {
    // q/k: row-major [wh][tok][d], 4 contiguous d per reg quad
#pragma unroll
    for (int mi = 0; mi < 4; ++mi) {
      int tok_g = bm * BM + wr * 64 + mi * 16 + l15;
      int win = tok_g >> 9, tk = tok_g & 511;
#pragma unroll
      for (int nj = 0; nj < 4; ++nj) {
        int c = bn * BN + wc * 64 + nj * 16 + lh * 4;  // global col (0..1023)
        int sel = c >> 9, cc = c & 511;
        int head = cc >> 6, d0 = cc & 63;
        *(ushort4*)(qkv_out + (size_t)sel * SEL_STRIDE +
                    (((size_t)(win * 8 + head)) * 512 + tk) * 64 + d0) =
            pack4(acc[mi][nj]);
      }
    }
  } else if (MODE == 0) {
    // v: transposed [wh][d][tok], 4 contiguous toks per reg quad
#pragma unroll
    for (int mi = 0; mi < 4; ++mi) {
      int tok0 = bm * BM + wr * 64 + mi * 16 + lh * 4;
      int win = tok0 >> 9, tk0 = tok0 & 511;
#pragma unroll
      for (int nj = 0; nj < 4; ++nj) {
        int cc = (bn - 8) * BN + wc * 64 + nj * 16 + l15;  // col within v (0..511)
        int head = cc >> 6, d = cc & 63;
        *(ushort4*)(qkv_out + 2 * (size_t)SEL_STRIDE +
                    (((size_t)(win * 8 + head)) * 64 + d) * 512 + tk0) =
            pack4(acc[mi][nj]);
      }
    }
  } else {
#pragma unroll
    for (int mi = 0; mi < 4; ++mi) {
      int row = bm * BM + wr * 64 + mi * 16 + lh * 4;
#pragma unroll
      for (int r = 0; r < 4; ++r) {
        int srow = win_to_src_row(row + r);
        float* op = out + (size_t)srow * CDIM;
#pragma unroll
        for (int nj = 0; nj < 4; ++nj) {
          int col = bn * BN + wc * 64 + nj * 16 + l15;
          op[col] = acc[mi][nj][r] + bias[col];
        }
      }
    }
  }
}

// ---------------- pass 2: windowed attention ----------------
// grid = 1024 blocks = (wh=512) x (qc=2 tiles of 256 rows); 256 threads = 4 waves.
// Each wave owns 64 q-rows (qi=0..3) -> K/V fragment loads amortized 4x; four
// independent qi chains give ILP to cover global/LDS latency.
__global__ __launch_bounds__(256, 2) void attn_kernel(const bf16* __restrict__ qkv_ws,
                                                      bf16* __restrict__ o_ws) {
  __shared__ __align__(16) bf16 Pl[4][4][16 * 64];  // [wave][qi] P tiles, swizzled
  int l2 = xcd_chunk(blockIdx.x, 1024);
  int wh = l2 >> 1, qc = l2 & 1;
  int win = wh >> 3, head = wh & 7;
  int t = threadIdx.x, lane = t & 63, w = t >> 6;
  int l15 = lane & 15, lh = lane >> 4;
  const bf16* qb = qkv_ws + (size_t)wh * (512 * 64);
  const bf16* kb = qb + SEL_STRIDE;
  const bf16* vtb = qkv_ws + 2 * (size_t)SEL_STRIDE + (size_t)wh * (64 * 512);

  const float c_scale = 0.18033688011112042f;  // 0.125 * log2(e)
  int q0 = qc * 256 + w * 64;
  bf16x8 qf[4][2];
#pragma unroll
  for (int qi = 0; qi < 4; ++qi)
#pragma unroll
    for (int kk = 0; kk < 2; ++kk)
      qf[qi][kk] = *(const bf16x8*)(qb + (size_t)(q0 + qi * 16 + l15) * 64 + kk * 32 + lh * 8);

  f32x4 acco[4][4] = {};
  float lsum[4][4] = {};
  for (int kt = 0; kt < 8; ++kt) {
    bf16x8 kf[4][2], vf[4][2];
#pragma unroll
    for (int kj = 0; kj < 4; ++kj) {
      int tok = kt * 64 + kj * 16 + l15;
#pragma unroll
      for (int kk = 0; kk < 2; ++kk)
        kf[kj][kk] = *(const bf16x8*)(kb + (size_t)tok * 64 + kk * 32 + lh * 8);
    }
#pragma unroll
    for (int nj = 0; nj < 4; ++nj) {
      int d = nj * 16 + l15;
#pragma unroll
      for (int kk = 0; kk < 2; ++kk)
        vf[nj][kk] = *(const bf16x8*)(vtb + (size_t)d * 512 + kt * 64 + kk * 32 + lh * 8);
    }
#pragma unroll
    for (int qi = 0; qi < 4; ++qi) {
      f32x4 s[4] = {};
#pragma unroll
      for (int kj = 0; kj < 4; ++kj)
#pragma unroll
        for (int kk = 0; kk < 2; ++kk)
          s[kj] = __builtin_amdgcn_mfma_f32_16x16x32_bf16(qf[qi][kk], kf[kj][kk], s[kj], 0, 0, 0);
#pragma unroll
      for (int kj = 0; kj < 4; ++kj)
#pragma unroll
        for (int r = 0; r < 4; ++r) {
          float p = __builtin_exp2f(s[kj][r] * c_scale);
          s[kj][r] = p;
          lsum[qi][r] += p;
        }
      char* myP = (char*)&Pl[w][qi][0];
#pragma unroll
      for (int kj = 0; kj < 4; ++kj)
#pragma unroll
        for (int r = 0; r < 4; ++r) {
          int prow = lh * 4 + r, pcol = kj * 16 + l15;
          *(bf16*)(myP + prow * 128 + ((pcol * 2) ^ ((prow & 7) << 4))) =
              __float2bfloat16(s[kj][r]);
        }
      bf16x8 pa[2];
#pragma unroll
      for (int kk = 0; kk < 2; ++kk)
        pa[kk] = *(const bf16x8*)(myP + l15 * 128 + ((kk * 64 + lh * 16) ^ ((l15 & 7) << 4)));
#pragma unroll
      for (int nj = 0; nj < 4; ++nj)
#pragma unroll
        for (int kk = 0; kk < 2; ++kk)
          acco[qi][nj] = __builtin_amdgcn_mfma_f32_16x16x32_bf16(pa[kk], vf[nj][kk],
                                                                 acco[qi][nj], 0, 0, 0);
    }
  }
#pragma unroll
  for (int qi = 0; qi < 4; ++qi) {
    float inv[4];
#pragma unroll
    for (int r = 0; r < 4; ++r) {
      float v = lsum[qi][r];
      v += __shfl_xor(v, 1);
      v += __shfl_xor(v, 2);
      v += __shfl_xor(v, 4);
      v += __shfl_xor(v, 8);
      inv[r] = __frcp_rn(v);
    }
#pragma unroll
    for (int nj = 0; nj < 4; ++nj)
#pragma unroll
      for (int r = 0; r < 4; ++r) {
        int row = q0 + qi * 16 + lh * 4 + r;
        int d = nj * 16 + l15;
        o_ws[((size_t)win * 512 + row) * 512 + head * 64 + d] =
            __float2bfloat16(acco[qi][nj][r] * inv[r]);
      }
  }
}

extern "C" void kernel_launch(void* const* d_in, const int* in_sizes, int n_in,
                              void* d_out, int out_size, void* d_ws, size_t ws_size,
                              hipStream_t stream) {
  const float* x = (const float*)d_in[0];
  const float* w_qkv = (const float*)d_in[1];
  const float* w_proj = (const float*)d_in[2];
  const float* b_proj = (const float*)d_in[3];
  float* out = (float*)d_out;

  const size_t OFF_QKV = 33554432;
  const size_t OFF_WQ = OFF_QKV + 100663296;
  const size_t OFF_WP = OFF_WQ + 1572864;
  const size_t NEED = OFF_WP + 524288;
  if (ws_size < NEED) return;

  char* ws = (char*)d_ws;
  bf16* xw = (bf16*)ws;
  bf16* qkv = (bf16*)(ws + OFF_QKV);
  bf16* wqkvT = (bf16*)(ws + OFF_WQ);
  bf16* wprojT = (bf16*)(ws + OFF_WP);
  bf16* o_ws = xw;  // attention does not read xw

  transpose_cvt_kernel<<<dim3(1536 / 32, 512 / 32), dim3(32, 8), 0, stream>>>(w_qkv, wqkvT, 512, 1536);
  transpose_cvt_kernel<<<dim3(512 / 32, 512 / 32), dim3(32, 8), 0, stream>>>(w_proj, wprojT, 512, 512);
  perm_x_kernel<<<2048, 256, 0, stream>>>(x, xw);
  // q/k tiles (swapped MFMA, packed row-major stores)
  gemm_bt_kernel<0, 1><<<256 * 8, 256, 0, stream>>>(xw, wqkvT, 8, 0, qkv, nullptr, nullptr);
  // v tiles (normal MFMA, packed transposed stores)
  gemm_bt_kernel<0, 0><<<256 * 4, 256, 0, stream>>>(xw, wqkvT, 4, 8, qkv, nullptr, nullptr);
  attn_kernel<<<1024, 256, 0, stream>>>(qkv, o_ws);
  gemm_bt_kernel<1, 0><<<256 * 4, 256, 0, stream>>>(o_ws, wprojT, 4, 0, nullptr, out, b_proj);
}

// Round 6
// 237.671 us; speedup vs baseline: 1.0557x; 1.0103x over previous
//
#include <hip/hip_runtime.h>
#include <hip/hip_bf16.h>

typedef __hip_bfloat16 bf16;
typedef __attribute__((ext_vector_type(8))) short bf16x8;
typedef __attribute__((ext_vector_type(4))) float f32x4;
typedef __attribute__((ext_vector_type(4))) unsigned int u32x4;

// Geometry (hardcoded): B=2, T=16, H=32, W=32, C=512, heads=8, hd=64,
// win=(8,8,8) -> no padding. 64 windows x 512 tokens; M = 32768 rows.
#define MROWS 32768
#define CDIM 512
#define SEL_STRIDE (512*512*64)  // elems per q/k/v section
// q,k sections: [wh=512][tok=512][d=64] row-major
// v section:    [wh=512][d=64][tok=512]  (transposed)

__device__ __forceinline__ int win_to_src_row(int m) {
  int win = m >> 9, l = m & 511;
  int b = win >> 5, rr = win & 31;
  int nt = rr >> 4, nh = (rr >> 2) & 3, nw = rr & 3;
  int wt = l >> 6, wh = (l >> 3) & 7, ww = l & 7;
  int tt = nt * 8 + wt, hh = nh * 8 + wh, wp = nw * 8 + ww;
  return (b << 14) + (tt << 10) + (hh << 5) + wp;
}

__device__ __forceinline__ unsigned short bf16bits(bf16 h) {
  return __builtin_bit_cast(unsigned short, h);
}

__device__ __forceinline__ ushort4 pack4(f32x4 a) {
  ushort4 o;
  o.x = bf16bits(__float2bfloat16(a[0]));
  o.y = bf16bits(__float2bfloat16(a[1]));
  o.z = bf16bits(__float2bfloat16(a[2]));
  o.w = bf16bits(__float2bfloat16(a[3]));
  return o;
}

__device__ __forceinline__ unsigned int cvtpk_bf16(float lo, float hi) {
  unsigned int r;
  asm("v_cvt_pk_bf16_f32 %0, %1, %2" : "=v"(r) : "v"(lo), "v"(hi));
  return r;
}

// XCD-chunked bijective block swizzle (requires n % 8 == 0)
__device__ __forceinline__ int xcd_chunk(int bx, int n) {
  return (bx & 7) * (n >> 3) + (bx >> 3);
}

// ---------------- pass 0a: weight transpose + fp32->bf16 ----------------
__global__ __launch_bounds__(256) void transpose_cvt_kernel(
    const float* __restrict__ src, bf16* __restrict__ dst, int R, int C) {
  __shared__ float tile[32][33];
  int bc = blockIdx.x * 32, br = blockIdx.y * 32;
  int tx = threadIdx.x, ty = threadIdx.y;  // (32,8)
#pragma unroll
  for (int i = 0; i < 32; i += 8)
    tile[ty + i][tx] = src[(size_t)(br + ty + i) * C + bc + tx];
  __syncthreads();
#pragma unroll
  for (int i = 0; i < 32; i += 8)
    dst[(size_t)(bc + ty + i) * R + br + tx] = __float2bfloat16(tile[tx][ty + i]);
}

// ---------------- pass 0b: x permute to window order + fp32->bf16 ----------------
__global__ __launch_bounds__(256) void perm_x_kernel(const float* __restrict__ x,
                                                     bf16* __restrict__ xw) {
  const int total = MROWS * (CDIM / 4);  // float4 units
  for (int i = blockIdx.x * 256 + threadIdx.x; i < total; i += 2048 * 256) {
    int m = i >> 7, c4 = (i & 127) * 4;
    int src = win_to_src_row(m);
    float4 v = *(const float4*)(x + (size_t)src * CDIM + c4);
    ushort4 o;
    o.x = bf16bits(__float2bfloat16(v.x));
    o.y = bf16bits(__float2bfloat16(v.y));
    o.z = bf16bits(__float2bfloat16(v.z));
    o.w = bf16bits(__float2bfloat16(v.w));
    *(ushort4*)(xw + (size_t)m * CDIM + c4) = o;
  }
}

// ---------------- shared GEMM: C[M,N] = A[M,512] @ Bt[N,512]^T ----------------
#define BM 128
#define BN 128
#define BK 64

__device__ __forceinline__ void gload16(const bf16* g, const bf16* l) {
  __builtin_amdgcn_global_load_lds(
      (const __attribute__((address_space(1))) unsigned int*)g,
      (__attribute__((address_space(3))) unsigned int*)l, 16, 0, 0);
}

// MODE 0: QKV, single dispatch, Ntiles=12.
//   bn<8  (cols 0-1023, q/k): swapped MFMA -> packed row-major ushort4 stores.
//   bn>=8 (cols 1024-1535, v): normal MFMA -> packed transposed ushort4 stores.
// MODE 1: proj: swapped MFMA -> float4 stores with window un-partition + bias.
template <int MODE>
__global__ __launch_bounds__(256) void gemm_bt_kernel(
    const bf16* __restrict__ A, const bf16* __restrict__ Bt, int Ntiles,
    bf16* __restrict__ qkv_out, float* __restrict__ out,
    const float* __restrict__ bias) {
  __shared__ __align__(16) bf16 Asl[BM * BK];
  __shared__ __align__(16) bf16 Bsl[BN * BK];
  const int K = 512;
  int l2 = xcd_chunk(blockIdx.x, gridDim.x);
  int bn = (l2 >> 3) % Ntiles;
  int bm = (l2 & 7) + (l2 / (8 * Ntiles)) * 8;
  int t = threadIdx.x, lane = t & 63, w = t >> 6;
  int wr = w >> 1, wc = w & 1;  // 2x2 waves, 64x64 each
  int l15 = lane & 15, lh = lane >> 4;
  const bool swp = (MODE == 1) || (bn < 8);
  f32x4 acc[4][4] = {};

  for (int kt = 0; kt < K; kt += BK) {
    __syncthreads();
#pragma unroll
    for (int i = 0; i < 4; ++i) {
      int f = i * 256 + t;
      int row = f >> 3, cb = f & 7;
      gload16(A + (size_t)(bm * BM + row) * K + kt + cb * 8,
              &Asl[(i * 256 + w * 64) * 8]);
    }
#pragma unroll
    for (int i = 0; i < 4; ++i) {
      int f = i * 256 + t;
      int row = f >> 3, cb = f & 7;
      gload16(Bt + (size_t)(bn * BN + row) * K + kt + cb * 8,
              &Bsl[(i * 256 + w * 64) * 8]);
    }
    __syncthreads();
    if (swp) {
#pragma unroll
      for (int kk = 0; kk < 2; ++kk) {
        bf16x8 af[4], bfr[4];
#pragma unroll
        for (int mi = 0; mi < 4; ++mi)
          af[mi] = *(const bf16x8*)&Asl[(wr * 64 + mi * 16 + l15) * BK + kk * 32 + lh * 8];
#pragma unroll
        for (int nj = 0; nj < 4; ++nj)
          bfr[nj] = *(const bf16x8*)&Bsl[(wc * 64 + nj * 16 + l15) * BK + kk * 32 + lh * 8];
#pragma unroll
        for (int mi = 0; mi < 4; ++mi)
#pragma unroll
          for (int nj = 0; nj < 4; ++nj)  // D[c][row]: col(l15)=A-row, row(lh*4+r)=B-row(c)
            acc[mi][nj] = __builtin_amdgcn_mfma_f32_16x16x32_bf16(
                bfr[nj], af[mi], acc[mi][nj], 0, 0, 0);
      }
    } else {
#pragma unroll
      for (int kk = 0; kk < 2; ++kk) {
        bf16x8 af[4], bfr[4];
#pragma unroll
        for (int mi = 0; mi < 4; ++mi)
          af[mi] = *(const bf16x8*)&Asl[(wr * 64 + mi * 16 + l15) * BK + kk * 32 + lh * 8];
#pragma unroll
        for (int nj = 0; nj < 4; ++nj)
          bfr[nj] = *(const bf16x8*)&Bsl[(wc * 64 + nj * 16 + l15) * BK + kk * 32 + lh * 8];
#pragma unroll
        for (int mi = 0; mi < 4; ++mi)
#pragma unroll
          for (int nj = 0; nj < 4; ++nj)
            acc[mi][nj] = __builtin_amdgcn_mfma_f32_16x16x32_bf16(
                af[mi], bfr[nj], acc[mi][nj], 0, 0, 0);
      }
    }
  }

  if (MODE == 0) {
    if (bn < 8) {
      // q/k: row-major [wh][tok][d], 4 contiguous d per reg quad
#pragma unroll
      for (int mi = 0; mi < 4; ++mi) {
        int tok_g = bm * BM + wr * 64 + mi * 16 + l15;
        int win = tok_g >> 9, tk = tok_g & 511;
#pragma unroll
        for (int nj = 0; nj < 4; ++nj) {
          int c = bn * BN + wc * 64 + nj * 16 + lh * 4;  // global col (0..1023)
          int sel = c >> 9, cc = c & 511;
          int head = cc >> 6, d0 = cc & 63;
          *(ushort4*)(qkv_out + (size_t)sel * SEL_STRIDE +
                      (((size_t)(win * 8 + head)) * 512 + tk) * 64 + d0) =
              pack4(acc[mi][nj]);
        }
      }
    } else {
      // v: transposed [wh][d][tok], 4 contiguous toks per reg quad
#pragma unroll
      for (int mi = 0; mi < 4; ++mi) {
        int tok0 = bm * BM + wr * 64 + mi * 16 + lh * 4;
        int win = tok0 >> 9, tk0 = tok0 & 511;
#pragma unroll
        for (int nj = 0; nj < 4; ++nj) {
          int cc = (bn - 8) * BN + wc * 64 + nj * 16 + l15;  // col within v (0..511)
          int head = cc >> 6, d = cc & 63;
          *(ushort4*)(qkv_out + 2 * (size_t)SEL_STRIDE +
                      (((size_t)(win * 8 + head)) * 64 + d) * 512 + tk0) =
              pack4(acc[mi][nj]);
        }
      }
    }
  } else {
    // proj, swapped: col(l15) = out-row, row(lh*4+r) = out-col quad -> float4
#pragma unroll
    for (int mi = 0; mi < 4; ++mi) {
      int row = bm * BM + wr * 64 + mi * 16 + l15;
      int srow = win_to_src_row(row);
      float* op = out + (size_t)srow * CDIM;
#pragma unroll
      for (int nj = 0; nj < 4; ++nj) {
        int col = bn * BN + wc * 64 + nj * 16 + lh * 4;
        float4 bv = *(const float4*)(bias + col);
        float4 v;
        v.x = acc[mi][nj][0] + bv.x;
        v.y = acc[mi][nj][1] + bv.y;
        v.z = acc[mi][nj][2] + bv.z;
        v.w = acc[mi][nj][3] + bv.w;
        *(float4*)(op + col) = v;
      }
    }
  }
}

// ---------------- pass 2: windowed attention (zero LDS, in-register P) --------
// grid = 1024 blocks = (wh=512) x (qc=2 tiles of 256 rows); 256 threads = 4 waves,
// each wave owns 64 q-rows (qi=0..3). Swapped QK^T: lane l15 = q-row, so softmax
// rows are lane-local; P redistributed to the PV A-fragment with cvt_pk +
// ds_bpermute (no LDS round-trip). K chunk = 32 tokens.
__global__ __launch_bounds__(256, 2) void attn_kernel(const bf16* __restrict__ qkv_ws,
                                                      bf16* __restrict__ o_ws) {
  int l2 = xcd_chunk(blockIdx.x, 1024);
  int wh = l2 >> 1, qc = l2 & 1;
  int win = wh >> 3, head = wh & 7;
  int t = threadIdx.x, lane = t & 63, w = t >> 6;
  int l15 = lane & 15, lh = lane >> 4;
  const bf16* qb = qkv_ws + (size_t)wh * (512 * 64);
  const bf16* kb = qb + SEL_STRIDE;
  const bf16* vtb = qkv_ws + 2 * (size_t)SEL_STRIDE + (size_t)wh * (64 * 512);

  const float c_scale = 0.18033688011112042f;  // 0.125 * log2(e)
  int q0 = qc * 256 + w * 64;
  bf16x8 qf[4][2];
#pragma unroll
  for (int qi = 0; qi < 4; ++qi)
#pragma unroll
    for (int kk = 0; kk < 2; ++kk)
      qf[qi][kk] = *(const bf16x8*)(qb + (size_t)(q0 + qi * 16 + l15) * 64 + kk * 32 + lh * 8);

  // bpermute byte-indices: dest (lh,m): src lane = ((2*lh + (m>>1))&3)*16 + l15
  int idx0 = (((((2 * lh + 0) & 3) << 4) + l15) << 2);
  int idx1 = (((((2 * lh + 1) & 3) << 4) + l15) << 2);
  int kjsel = lh >> 1;  // which kj register feeds this dest lane

  f32x4 acco[4][4] = {};
  float lsum[4] = {0.f, 0.f, 0.f, 0.f};
  for (int ck = 0; ck < 16; ++ck) {  // 32 tokens per chunk
    bf16x8 kf[2][2], vf[4];
#pragma unroll
    for (int kj = 0; kj < 2; ++kj) {
      int tok = ck * 32 + kj * 16 + l15;
#pragma unroll
      for (int kk = 0; kk < 2; ++kk)
        kf[kj][kk] = *(const bf16x8*)(kb + (size_t)tok * 64 + kk * 32 + lh * 8);
    }
#pragma unroll
    for (int nj = 0; nj < 4; ++nj)
      vf[nj] = *(const bf16x8*)(vtb + (size_t)(nj * 16 + l15) * 512 + ck * 32 + lh * 8);
#pragma unroll
    for (int qi = 0; qi < 4; ++qi) {
      // swapped QK^T: D[row=lh*4+r -> k-token][col=l15 -> q-row]
      f32x4 s0 = {}, s1 = {};
#pragma unroll
      for (int kk = 0; kk < 2; ++kk) {
        s0 = __builtin_amdgcn_mfma_f32_16x16x32_bf16(kf[0][kk], qf[qi][kk], s0, 0, 0, 0);
        s1 = __builtin_amdgcn_mfma_f32_16x16x32_bf16(kf[1][kk], qf[qi][kk], s1, 0, 0, 0);
      }
      float p00 = __builtin_exp2f(s0[0] * c_scale);
      float p01 = __builtin_exp2f(s0[1] * c_scale);
      float p02 = __builtin_exp2f(s0[2] * c_scale);
      float p03 = __builtin_exp2f(s0[3] * c_scale);
      float p10 = __builtin_exp2f(s1[0] * c_scale);
      float p11 = __builtin_exp2f(s1[1] * c_scale);
      float p12 = __builtin_exp2f(s1[2] * c_scale);
      float p13 = __builtin_exp2f(s1[3] * c_scale);
      lsum[qi] += ((p00 + p01) + (p02 + p03)) + ((p10 + p11) + (p12 + p13));
      unsigned int pk00 = cvtpk_bf16(p00, p01), pk01 = cvtpk_bf16(p02, p03);
      unsigned int pk10 = cvtpk_bf16(p10, p11), pk11 = cvtpk_bf16(p12, p13);
      // redistribute: pa.u32[m] = packed[kjsel][m&1] from lane idx(m>>1)
      unsigned int a0 = (unsigned int)__builtin_amdgcn_ds_bpermute(idx0, (int)pk00);
      unsigned int b0 = (unsigned int)__builtin_amdgcn_ds_bpermute(idx0, (int)pk10);
      unsigned int a1 = (unsigned int)__builtin_amdgcn_ds_bpermute(idx0, (int)pk01);
      unsigned int b1 = (unsigned int)__builtin_amdgcn_ds_bpermute(idx0, (int)pk11);
      unsigned int a2 = (unsigned int)__builtin_amdgcn_ds_bpermute(idx1, (int)pk00);
      unsigned int b2 = (unsigned int)__builtin_amdgcn_ds_bpermute(idx1, (int)pk10);
      unsigned int a3 = (unsigned int)__builtin_amdgcn_ds_bpermute(idx1, (int)pk01);
      unsigned int b3 = (unsigned int)__builtin_amdgcn_ds_bpermute(idx1, (int)pk11);
      u32x4 pu;
      pu[0] = kjsel ? b0 : a0;
      pu[1] = kjsel ? b1 : a1;
      pu[2] = kjsel ? b2 : a2;
      pu[3] = kjsel ? b3 : a3;
      bf16x8 pa = __builtin_bit_cast(bf16x8, pu);
#pragma unroll
      for (int nj = 0; nj < 4; ++nj)
        acco[qi][nj] = __builtin_amdgcn_mfma_f32_16x16x32_bf16(pa, vf[nj], acco[qi][nj], 0, 0, 0);
    }
  }
#pragma unroll
  for (int qi = 0; qi < 4; ++qi) {
    // lsum lives at lane l15 = q-row; reduce over lh groups, then fetch per-row
    float v = lsum[qi];
    v += __shfl_xor(v, 16);
    v += __shfl_xor(v, 32);
    float inv[4];
#pragma unroll
    for (int r = 0; r < 4; ++r) inv[r] = __frcp_rn(__shfl(v, lh * 4 + r));
#pragma unroll
    for (int nj = 0; nj < 4; ++nj)
#pragma unroll
      for (int r = 0; r < 4; ++r) {
        int row = q0 + qi * 16 + lh * 4 + r;
        int d = nj * 16 + l15;
        o_ws[((size_t)win * 512 + row) * 512 + head * 64 + d] =
            __float2bfloat16(acco[qi][nj][r] * inv[r]);
      }
  }
}

extern "C" void kernel_launch(void* const* d_in, const int* in_sizes, int n_in,
                              void* d_out, int out_size, void* d_ws, size_t ws_size,
                              hipStream_t stream) {
  const float* x = (const float*)d_in[0];
  const float* w_qkv = (const float*)d_in[1];
  const float* w_proj = (const float*)d_in[2];
  const float* b_proj = (const float*)d_in[3];
  float* out = (float*)d_out;

  const size_t OFF_QKV = 33554432;
  const size_t OFF_WQ = OFF_QKV + 100663296;
  const size_t OFF_WP = OFF_WQ + 1572864;
  const size_t NEED = OFF_WP + 524288;
  if (ws_size < NEED) return;

  char* ws = (char*)d_ws;
  bf16* xw = (bf16*)ws;
  bf16* qkv = (bf16*)(ws + OFF_QKV);
  bf16* wqkvT = (bf16*)(ws + OFF_WQ);
  bf16* wprojT = (bf16*)(ws + OFF_WP);
  bf16* o_ws = xw;  // attention does not read xw

  transpose_cvt_kernel<<<dim3(1536 / 32, 512 / 32), dim3(32, 8), 0, stream>>>(w_qkv, wqkvT, 512, 1536);
  transpose_cvt_kernel<<<dim3(512 / 32, 512 / 32), dim3(32, 8), 0, stream>>>(w_proj, wprojT, 512, 512);
  perm_x_kernel<<<2048, 256, 0, stream>>>(x, xw);
  gemm_bt_kernel<0><<<256 * 12, 256, 0, stream>>>(xw, wqkvT, 12, qkv, nullptr, nullptr);
  attn_kernel<<<1024, 256, 0, stream>>>(qkv, o_ws);
  gemm_bt_kernel<1><<<256 * 4, 256, 0, stream>>>(o_ws, wprojT, 4, nullptr, out, b_proj);
}

// Round 7
// 235.511 us; speedup vs baseline: 1.0654x; 1.0092x over previous
//
#include <hip/hip_runtime.h>
#include <hip/hip_bf16.h>

typedef __hip_bfloat16 bf16;
typedef __attribute__((ext_vector_type(8))) short bf16x8;
typedef __attribute__((ext_vector_type(4))) float f32x4;
typedef __attribute__((ext_vector_type(4))) unsigned int u32x4;

// Geometry (hardcoded): B=2, T=16, H=32, W=32, C=512, heads=8, hd=64,
// win=(8,8,8) -> no padding. 64 windows x 512 tokens; M = 32768 rows.
#define MROWS 32768
#define CDIM 512
#define SEL_STRIDE (512*512*64)  // elems per q/k/v section
// q,k sections: [wh=512][tok=512][d=64] row-major
// v section:    [wh=512][d=64][tok=512]  (transposed)

__device__ __forceinline__ int win_to_src_row(int m) {
  int win = m >> 9, l = m & 511;
  int b = win >> 5, rr = win & 31;
  int nt = rr >> 4, nh = (rr >> 2) & 3, nw = rr & 3;
  int wt = l >> 6, wh = (l >> 3) & 7, ww = l & 7;
  int tt = nt * 8 + wt, hh = nh * 8 + wh, wp = nw * 8 + ww;
  return (b << 14) + (tt << 10) + (hh << 5) + wp;
}

__device__ __forceinline__ unsigned short bf16bits(bf16 h) {
  return __builtin_bit_cast(unsigned short, h);
}

__device__ __forceinline__ ushort4 pack4(f32x4 a) {
  ushort4 o;
  o.x = bf16bits(__float2bfloat16(a[0]));
  o.y = bf16bits(__float2bfloat16(a[1]));
  o.z = bf16bits(__float2bfloat16(a[2]));
  o.w = bf16bits(__float2bfloat16(a[3]));
  return o;
}

__device__ __forceinline__ unsigned int cvtpk_bf16(float lo, float hi) {
  unsigned int r;
  asm("v_cvt_pk_bf16_f32 %0, %1, %2" : "=v"(r) : "v"(lo), "v"(hi));
  return r;
}

// XCD-chunked bijective block swizzle (requires n % 8 == 0)
__device__ __forceinline__ int xcd_chunk(int bx, int n) {
  return (bx & 7) * (n >> 3) + (bx >> 3);
}

// ---------------- pass 0a: weight transpose + fp32->bf16 ----------------
__global__ __launch_bounds__(256) void transpose_cvt_kernel(
    const float* __restrict__ src, bf16* __restrict__ dst, int R, int C) {
  __shared__ float tile[32][33];
  int bc = blockIdx.x * 32, br = blockIdx.y * 32;
  int tx = threadIdx.x, ty = threadIdx.y;  // (32,8)
#pragma unroll
  for (int i = 0; i < 32; i += 8)
    tile[ty + i][tx] = src[(size_t)(br + ty + i) * C + bc + tx];
  __syncthreads();
#pragma unroll
  for (int i = 0; i < 32; i += 8)
    dst[(size_t)(bc + ty + i) * R + br + tx] = __float2bfloat16(tile[tx][ty + i]);
}

// ---------------- pass 0b: x permute to window order + fp32->bf16 ----------------
__global__ __launch_bounds__(256) void perm_x_kernel(const float* __restrict__ x,
                                                     bf16* __restrict__ xw) {
  const int total = MROWS * (CDIM / 4);  // float4 units
  for (int i = blockIdx.x * 256 + threadIdx.x; i < total; i += 2048 * 256) {
    int m = i >> 7, c4 = (i & 127) * 4;
    int src = win_to_src_row(m);
    float4 v = *(const float4*)(x + (size_t)src * CDIM + c4);
    ushort4 o;
    o.x = bf16bits(__float2bfloat16(v.x));
    o.y = bf16bits(__float2bfloat16(v.y));
    o.z = bf16bits(__float2bfloat16(v.z));
    o.w = bf16bits(__float2bfloat16(v.w));
    *(ushort4*)(xw + (size_t)m * CDIM + c4) = o;
  }
}

// ---------------- shared GEMM: C[M,N] = A[M,512] @ Bt[N,512]^T ----------------
#define BM 128
#define BN 128
#define BK 64

__device__ __forceinline__ void gload16(const bf16* g, const bf16* l) {
  __builtin_amdgcn_global_load_lds(
      (const __attribute__((address_space(1))) unsigned int*)g,
      (__attribute__((address_space(3))) unsigned int*)l, 16, 0, 0);
}

// MODE 0, SWAP 1: q/k tiles (bn0=0, cols 0-1023). Swapped MFMA: regs hold 4
//   contiguous d -> packed ushort4 row-major scatter.
// MODE 0, SWAP 0: v tiles (bn0=8, cols 1024-1535). Normal MFMA: regs hold 4
//   contiguous toks -> packed ushort4 transposed scatter.
// MODE 1, SWAP 1: proj: swapped MFMA -> float4 stores, un-partition + bias.
template <int MODE, int SWAP>
__global__ __launch_bounds__(256) void gemm_bt_kernel(
    const bf16* __restrict__ A, const bf16* __restrict__ Bt, int Ntiles, int bn0,
    bf16* __restrict__ qkv_out, float* __restrict__ out,
    const float* __restrict__ bias) {
  __shared__ __align__(16) bf16 Asl[BM * BK];
  __shared__ __align__(16) bf16 Bsl[BN * BK];
  const int K = 512;
  int l2 = xcd_chunk(blockIdx.x, gridDim.x);
  int bn = bn0 + (l2 >> 3) % Ntiles;
  int bm = (l2 & 7) + (l2 / (8 * Ntiles)) * 8;
  int t = threadIdx.x, lane = t & 63, w = t >> 6;
  int wr = w >> 1, wc = w & 1;  // 2x2 waves, 64x64 each
  int l15 = lane & 15, lh = lane >> 4;
  f32x4 acc[4][4] = {};

  for (int kt = 0; kt < K; kt += BK) {
    __syncthreads();
#pragma unroll
    for (int i = 0; i < 4; ++i) {
      int f = i * 256 + t;
      int row = f >> 3, cb = f & 7;
      gload16(A + (size_t)(bm * BM + row) * K + kt + cb * 8,
              &Asl[(i * 256 + w * 64) * 8]);
    }
#pragma unroll
    for (int i = 0; i < 4; ++i) {
      int f = i * 256 + t;
      int row = f >> 3, cb = f & 7;
      gload16(Bt + (size_t)(bn * BN + row) * K + kt + cb * 8,
              &Bsl[(i * 256 + w * 64) * 8]);
    }
    __syncthreads();
#pragma unroll
    for (int kk = 0; kk < 2; ++kk) {
      bf16x8 af[4], bfr[4];
#pragma unroll
      for (int mi = 0; mi < 4; ++mi)
        af[mi] = *(const bf16x8*)&Asl[(wr * 64 + mi * 16 + l15) * BK + kk * 32 + lh * 8];
#pragma unroll
      for (int nj = 0; nj < 4; ++nj)
        bfr[nj] = *(const bf16x8*)&Bsl[(wc * 64 + nj * 16 + l15) * BK + kk * 32 + lh * 8];
#pragma unroll
      for (int mi = 0; mi < 4; ++mi)
#pragma unroll
        for (int nj = 0; nj < 4; ++nj) {
          if (SWAP)  // D[c][row]: col(l15)=A-row, row(lh*4+r)=B-row(c)
            acc[mi][nj] = __builtin_amdgcn_mfma_f32_16x16x32_bf16(
                bfr[nj], af[mi], acc[mi][nj], 0, 0, 0);
          else       // D[row][c]: row(lh*4+r)=A-row, col(l15)=B-row(c)
            acc[mi][nj] = __builtin_amdgcn_mfma_f32_16x16x32_bf16(
                af[mi], bfr[nj], acc[mi][nj], 0, 0, 0);
        }
    }
  }

  if (MODE == 0 && SWAP == 1) {
    // q/k: row-major [wh][tok][d], 4 contiguous d per reg quad
#pragma unroll
    for (int mi = 0; mi < 4; ++mi) {
      int tok_g = bm * BM + wr * 64 + mi * 16 + l15;
      int win = tok_g >> 9, tk = tok_g & 511;
#pragma unroll
      for (int nj = 0; nj < 4; ++nj) {
        int c = bn * BN + wc * 64 + nj * 16 + lh * 4;  // global col (0..1023)
        int sel = c >> 9, cc = c & 511;
        int head = cc >> 6, d0 = cc & 63;
        *(ushort4*)(qkv_out + (size_t)sel * SEL_STRIDE +
                    (((size_t)(win * 8 + head)) * 512 + tk) * 64 + d0) =
            pack4(acc[mi][nj]);
      }
    }
  } else if (MODE == 0) {
    // v: transposed [wh][d][tok], 4 contiguous toks per reg quad
#pragma unroll
    for (int mi = 0; mi < 4; ++mi) {
      int tok0 = bm * BM + wr * 64 + mi * 16 + lh * 4;
      int win = tok0 >> 9, tk0 = tok0 & 511;
#pragma unroll
      for (int nj = 0; nj < 4; ++nj) {
        int cc = (bn - 8) * BN + wc * 64 + nj * 16 + l15;  // col within v (0..511)
        int head = cc >> 6, d = cc & 63;
        *(ushort4*)(qkv_out + 2 * (size_t)SEL_STRIDE +
                    (((size_t)(win * 8 + head)) * 64 + d) * 512 + tk0) =
            pack4(acc[mi][nj]);
      }
    }
  } else {
    // proj, swapped: col(l15) = out-row, row(lh*4+r) = out-col quad -> float4
#pragma unroll
    for (int mi = 0; mi < 4; ++mi) {
      int row = bm * BM + wr * 64 + mi * 16 + l15;
      int srow = win_to_src_row(row);
      float* op = out + (size_t)srow * CDIM;
#pragma unroll
      for (int nj = 0; nj < 4; ++nj) {
        int col = bn * BN + wc * 64 + nj * 16 + lh * 4;
        float4 bv = *(const float4*)(bias + col);
        float4 v;
        v.x = acc[mi][nj][0] + bv.x;
        v.y = acc[mi][nj][1] + bv.y;
        v.z = acc[mi][nj][2] + bv.z;
        v.w = acc[mi][nj][3] + bv.w;
        *(float4*)(op + col) = v;
      }
    }
  }
}

// ---------------- pass 2: windowed attention (zero LDS, in-register P) --------
// grid = 1024 blocks = (wh=512) x (qc=2 tiles of 256 rows); 256 threads = 4 waves,
// each wave owns 64 q-rows (qi=0..3). Swapped QK^T: lane l15 = q-row, so softmax
// rows are lane-local; P redistributed to the PV A-fragment with cvt_pk +
// ds_bpermute (no LDS round-trip). K chunk = 32 tokens.
__global__ __launch_bounds__(256, 2) void attn_kernel(const bf16* __restrict__ qkv_ws,
                                                      bf16* __restrict__ o_ws) {
  int l2 = xcd_chunk(blockIdx.x, 1024);
  int wh = l2 >> 1, qc = l2 & 1;
  int win = wh >> 3, head = wh & 7;
  int t = threadIdx.x, lane = t & 63, w = t >> 6;
  int l15 = lane & 15, lh = lane >> 4;
  const bf16* qb = qkv_ws + (size_t)wh * (512 * 64);
  const bf16* kb = qb + SEL_STRIDE;
  const bf16* vtb = qkv_ws + 2 * (size_t)SEL_STRIDE + (size_t)wh * (64 * 512);

  const float c_scale = 0.18033688011112042f;  // 0.125 * log2(e)
  int q0 = qc * 256 + w * 64;
  bf16x8 qf[4][2];
#pragma unroll
  for (int qi = 0; qi < 4; ++qi)
#pragma unroll
    for (int kk = 0; kk < 2; ++kk)
      qf[qi][kk] = *(const bf16x8*)(qb + (size_t)(q0 + qi * 16 + l15) * 64 + kk * 32 + lh * 8);

  // bpermute byte-indices: dest (lh,m): src lane = ((2*lh + (m>>1))&3)*16 + l15
  int idx0 = (((((2 * lh + 0) & 3) << 4) + l15) << 2);
  int idx1 = (((((2 * lh + 1) & 3) << 4) + l15) << 2);
  int kjsel = lh >> 1;  // which kj register feeds this dest lane

  f32x4 acco[4][4] = {};
  float lsum[4] = {0.f, 0.f, 0.f, 0.f};
  for (int ck = 0; ck < 16; ++ck) {  // 32 tokens per chunk
    bf16x8 kf[2][2], vf[4];
#pragma unroll
    for (int kj = 0; kj < 2; ++kj) {
      int tok = ck * 32 + kj * 16 + l15;
#pragma unroll
      for (int kk = 0; kk < 2; ++kk)
        kf[kj][kk] = *(const bf16x8*)(kb + (size_t)tok * 64 + kk * 32 + lh * 8);
    }
#pragma unroll
    for (int nj = 0; nj < 4; ++nj)
      vf[nj] = *(const bf16x8*)(vtb + (size_t)(nj * 16 + l15) * 512 + ck * 32 + lh * 8);
#pragma unroll
    for (int qi = 0; qi < 4; ++qi) {
      // swapped QK^T: D[row=lh*4+r -> k-token][col=l15 -> q-row]
      f32x4 s0 = {}, s1 = {};
#pragma unroll
      for (int kk = 0; kk < 2; ++kk) {
        s0 = __builtin_amdgcn_mfma_f32_16x16x32_bf16(kf[0][kk], qf[qi][kk], s0, 0, 0, 0);
        s1 = __builtin_amdgcn_mfma_f32_16x16x32_bf16(kf[1][kk], qf[qi][kk], s1, 0, 0, 0);
      }
      float p00 = __builtin_exp2f(s0[0] * c_scale);
      float p01 = __builtin_exp2f(s0[1] * c_scale);
      float p02 = __builtin_exp2f(s0[2] * c_scale);
      float p03 = __builtin_exp2f(s0[3] * c_scale);
      float p10 = __builtin_exp2f(s1[0] * c_scale);
      float p11 = __builtin_exp2f(s1[1] * c_scale);
      float p12 = __builtin_exp2f(s1[2] * c_scale);
      float p13 = __builtin_exp2f(s1[3] * c_scale);
      lsum[qi] += ((p00 + p01) + (p02 + p03)) + ((p10 + p11) + (p12 + p13));
      unsigned int pk00 = cvtpk_bf16(p00, p01), pk01 = cvtpk_bf16(p02, p03);
      unsigned int pk10 = cvtpk_bf16(p10, p11), pk11 = cvtpk_bf16(p12, p13);
      // redistribute: pa.u32[m] = packed[kjsel][m&1] from lane idx(m>>1)
      unsigned int a0 = (unsigned int)__builtin_amdgcn_ds_bpermute(idx0, (int)pk00);
      unsigned int b0 = (unsigned int)__builtin_amdgcn_ds_bpermute(idx0, (int)pk10);
      unsigned int a1 = (unsigned int)__builtin_amdgcn_ds_bpermute(idx0, (int)pk01);
      unsigned int b1 = (unsigned int)__builtin_amdgcn_ds_bpermute(idx0, (int)pk11);
      unsigned int a2 = (unsigned int)__builtin_amdgcn_ds_bpermute(idx1, (int)pk00);
      unsigned int b2 = (unsigned int)__builtin_amdgcn_ds_bpermute(idx1, (int)pk10);
      unsigned int a3 = (unsigned int)__builtin_amdgcn_ds_bpermute(idx1, (int)pk01);
      unsigned int b3 = (unsigned int)__builtin_amdgcn_ds_bpermute(idx1, (int)pk11);
      u32x4 pu;
      pu[0] = kjsel ? b0 : a0;
      pu[1] = kjsel ? b1 : a1;
      pu[2] = kjsel ? b2 : a2;
      pu[3] = kjsel ? b3 : a3;
      bf16x8 pa = __builtin_bit_cast(bf16x8, pu);
#pragma unroll
      for (int nj = 0; nj < 4; ++nj)
        acco[qi][nj] = __builtin_amdgcn_mfma_f32_16x16x32_bf16(pa, vf[nj], acco[qi][nj], 0, 0, 0);
    }
  }
#pragma unroll
  for (int qi = 0; qi < 4; ++qi) {
    // lsum lives at lane l15 = q-row; reduce over lh groups, then fetch per-row
    float v = lsum[qi];
    v += __shfl_xor(v, 16);
    v += __shfl_xor(v, 32);
    float inv[4];
#pragma unroll
    for (int r = 0; r < 4; ++r) inv[r] = __frcp_rn(__shfl(v, lh * 4 + r));
#pragma unroll
    for (int nj = 0; nj < 4; ++nj)
#pragma unroll
      for (int r = 0; r < 4; ++r) {
        int row = q0 + qi * 16 + lh * 4 + r;
        int d = nj * 16 + l15;
        o_ws[((size_t)win * 512 + row) * 512 + head * 64 + d] =
            __float2bfloat16(acco[qi][nj][r] * inv[r]);
      }
  }
}

extern "C" void kernel_launch(void* const* d_in, const int* in_sizes, int n_in,
                              void* d_out, int out_size, void* d_ws, size_t ws_size,
                              hipStream_t stream) {
  const float* x = (const float*)d_in[0];
  const float* w_qkv = (const float*)d_in[1];
  const float* w_proj = (const float*)d_in[2];
  const float* b_proj = (const float*)d_in[3];
  float* out = (float*)d_out;

  const size_t OFF_QKV = 33554432;
  const size_t OFF_WQ = OFF_QKV + 100663296;
  const size_t OFF_WP = OFF_WQ + 1572864;
  const size_t NEED = OFF_WP + 524288;
  if (ws_size < NEED) return;

  char* ws = (char*)d_ws;
  bf16* xw = (bf16*)ws;
  bf16* qkv = (bf16*)(ws + OFF_QKV);
  bf16* wqkvT = (bf16*)(ws + OFF_WQ);
  bf16* wprojT = (bf16*)(ws + OFF_WP);
  bf16* o_ws = xw;  // attention does not read xw

  transpose_cvt_kernel<<<dim3(1536 / 32, 512 / 32), dim3(32, 8), 0, stream>>>(w_qkv, wqkvT, 512, 1536);
  transpose_cvt_kernel<<<dim3(512 / 32, 512 / 32), dim3(32, 8), 0, stream>>>(w_proj, wprojT, 512, 512);
  perm_x_kernel<<<2048, 256, 0, stream>>>(x, xw);
  // q/k tiles (swapped MFMA, packed row-major stores)
  gemm_bt_kernel<0, 1><<<256 * 8, 256, 0, stream>>>(xw, wqkvT, 8, 0, qkv, nullptr, nullptr);
  // v tiles (normal MFMA, packed transposed stores)
  gemm_bt_kernel<0, 0><<<256 * 4, 256, 0, stream>>>(xw, wqkvT, 4, 8, qkv, nullptr, nullptr);
  attn_kernel<<<1024, 256, 0, stream>>>(qkv, o_ws);
  gemm_bt_kernel<1, 1><<<256 * 4, 256, 0, stream>>>(o_ws, wprojT, 4, 0, nullptr, out, b_proj);
}